// Round 1
// baseline (3107.735 us; speedup 1.0000x reference)
//
#include <hip/hip_runtime.h>
#include <hip/hip_bf16.h>

#define BATCH 256
#define SEQ   256
#define IND   128
#define HID   1024
#define OUTD  10

#define NCOLG 32           // 32 column groups of 32 cols
#define NROWG 8            // 8 row groups of 32 rows
#define CTR_OFF (2*BATCH*HID)   // counters after Hbuf, in bf16 elements

typedef __bf16 bf16x8 __attribute__((ext_vector_type(8)));
typedef float  f32x16 __attribute__((ext_vector_type(16)));

__device__ __forceinline__ float fast_tanh(float z) {
    float e = __expf(-2.0f * fabsf(z));
    float t = (1.0f - e) / (1.0f + e);
    return copysignf(t, z);
}

__global__ __launch_bounds__(256, 1)
void rnn_persistent(const float* __restrict__ x,
                    const float* __restrict__ Whx,
                    const float* __restrict__ Whh,
                    const float* __restrict__ bh,
                    const float* __restrict__ Why,
                    const float* __restrict__ bo,
                    float* __restrict__ out,
                    __bf16* __restrict__ ws)
{
    const int tid  = threadIdx.x;
    const int lane = tid & 63;
    const int wave = tid >> 6;
    const int bx   = blockIdx.x;
    const int colg = bx & (NCOLG-1);
    const int rowg = bx >> 5;
    const int c0 = colg * 32;
    const int r0 = rowg * 32;
    const int ln31  = lane & 31;
    const int lhalf = lane >> 5;

    __bf16* hb = ws;
    int* ctr = (int*)(ws + CTR_OFF) + rowg * 64;  // 256B-padded per group

    __shared__ float red[4][32][32];   // 16 KB: cross-wave K-reduction

    // ---- one-time: register-resident B fragments, hi/lo split ----
    // B-frag layout (32x32x16): n = lane&31, k = (lane>>5)*8 + j
    bf16x8 whh_hi[16], whh_lo[16];
    {
        const int nn = c0 + ln31;
        #pragma unroll
        for (int kk = 0; kk < 16; ++kk) {
            const int kb = wave*256 + kk*16 + lhalf*8;
            #pragma unroll
            for (int j = 0; j < 8; ++j) {
                float v = Whh[(size_t)(kb + j)*HID + nn];
                __bf16 h = (__bf16)v;
                whh_hi[kk][j] = h;
                whh_lo[kk][j] = (__bf16)(v - (float)h);
            }
        }
    }
    bf16x8 whx_hi[2], whx_lo[2];
    {
        const int nn = c0 + ln31;
        #pragma unroll
        for (int kk = 0; kk < 2; ++kk) {
            const int kb = wave*32 + kk*16 + lhalf*8;
            #pragma unroll
            for (int j = 0; j < 8; ++j) {
                float v = Whx[(size_t)(kb + j)*HID + nn];
                __bf16 h = (__bf16)v;
                whx_hi[kk][j] = h;
                whx_lo[kk][j] = (__bf16)(v - (float)h);
            }
        }
    }
    const float bh_c = bh[c0 + (tid & 31)];
    const size_t xrow_base = (size_t)(r0 + ln31) * (SEQ*IND) + wave*32 + lhalf*8;

    for (int t = 0; t < SEQ; ++t) {
        const int cur = t & 1;
        const int nxt = cur ^ 1;
        f32x16 acc0{}, acc1{};

        // ---- x(t) contribution: independent of h(t), done BEFORE barrier wait.
        // 3-pass hi/lo split: AhiBhi + AhiBlo + AloBhi
        {
            const float* xp = x + xrow_base + (size_t)t*IND;
            #pragma unroll
            for (int kk = 0; kk < 2; ++kk) {
                const float4* p = (const float4*)(xp + kk*16);
                float4 v0 = p[0], v1 = p[1];
                float vv[8] = {v0.x,v0.y,v0.z,v0.w,v1.x,v1.y,v1.z,v1.w};
                bf16x8 ahi, alo;
                #pragma unroll
                for (int j = 0; j < 8; ++j) {
                    __bf16 h = (__bf16)vv[j];
                    ahi[j] = h;
                    alo[j] = (__bf16)(vv[j] - (float)h);
                }
                acc0 = __builtin_amdgcn_mfma_f32_32x32x16_bf16(ahi, whx_hi[kk], acc0, 0,0,0);
                acc1 = __builtin_amdgcn_mfma_f32_32x32x16_bf16(ahi, whx_lo[kk], acc1, 0,0,0);
                acc0 = __builtin_amdgcn_mfma_f32_32x32x16_bf16(alo, whx_hi[kk], acc0, 0,0,0);
            }
        }

        // ---- wait for h(t): row-group barrier (32 arrivals/step, monotonic ctr)
        if (tid == 0) {
            const int target = 32*t;
            while (__hip_atomic_load(ctr, __ATOMIC_RELAXED, __HIP_MEMORY_SCOPE_AGENT) < target) { }
            __builtin_amdgcn_fence(__ATOMIC_ACQUIRE, "agent");
        }
        __syncthreads();

        // ---- h(t) @ Whh: A-frag = 8 consecutive bf16 of row (r0+ln31), 16B load
        {
            const bf16x8* ar = (const bf16x8*)(hb + (size_t)cur*BATCH*HID
                                 + (size_t)(r0+ln31)*HID + wave*256 + lhalf*8);
            #pragma unroll
            for (int kk = 0; kk < 16; ++kk) {
                bf16x8 a = ar[kk*2];
                acc0 = __builtin_amdgcn_mfma_f32_32x32x16_bf16(a, whh_hi[kk], acc0, 0,0,0);
                acc1 = __builtin_amdgcn_mfma_f32_32x32x16_bf16(a, whh_lo[kk], acc1, 0,0,0);
            }
        }

        // ---- cross-wave K reduction through LDS
        // C/D layout (32x32): col=lane&31, row=(reg&3)+8*(reg>>2)+4*(lane>>5)
        #pragma unroll
        for (int r = 0; r < 16; ++r) {
            const int row = (r & 3) + 8*(r >> 2) + 4*lhalf;
            red[wave][row][ln31] = acc0[r] + acc1[r];
        }
        __syncthreads();
        {
            const int col = tid & 31;
            const int rb  = (tid >> 5) * 4;
            __bf16* hn = hb + (size_t)nxt*BATCH*HID + c0 + col;
            #pragma unroll
            for (int rr = 0; rr < 4; ++rr) {
                const int row = rb + rr;
                float z = red[0][row][col] + red[1][row][col]
                        + red[2][row][col] + red[3][row][col] + bh_c;
                hn[(size_t)(r0+row)*HID] = (__bf16)fast_tanh(z);
            }
        }
        __syncthreads();   // drains vmcnt per-wave before arrival
        if (tid == 0) {
            __hip_atomic_fetch_add(ctr, 1, __ATOMIC_RELEASE, __HIP_MEMORY_SCOPE_AGENT);
        }
    }

    // ---- epilogue: colg==0 WG of each row-group computes o + softmax
    if (colg == 0) {
        if (tid == 0) {
            while (__hip_atomic_load(ctr, __ATOMIC_RELAXED, __HIP_MEMORY_SCOPE_AGENT) < 32*SEQ) { }
            __builtin_amdgcn_fence(__ATOMIC_ACQUIRE, "agent");
        }
        __syncthreads();
        const __bf16* hf = hb;          // after t=255, final h is in buffer 0
        float* obuf = &red[0][0][0];    // reuse LDS, 320 floats
        for (int idx = tid; idx < 32*OUTD; idx += 256) {
            const int row = idx / OUTD;
            const int c   = idx - row*OUTD;
            const __bf16* hr = hf + (size_t)(r0+row)*HID;
            float s = bo[c];
            #pragma unroll 8
            for (int k = 0; k < HID; ++k) s += (float)hr[k] * Why[(size_t)k*OUTD + c];
            obuf[idx] = s;
        }
        __syncthreads();
        if (tid < 32) {
            float m = -1e30f;
            #pragma unroll
            for (int c = 0; c < OUTD; ++c) m = fmaxf(m, obuf[tid*OUTD+c]);
            float e[OUTD]; float ssum = 0.f;
            #pragma unroll
            for (int c = 0; c < OUTD; ++c) { e[c] = __expf(obuf[tid*OUTD+c] - m); ssum += e[c]; }
            const float inv = 1.0f / ssum;
            #pragma unroll
            for (int c = 0; c < OUTD; ++c) out[(size_t)(r0+tid)*OUTD + c] = e[c]*inv;
        }
    }
}

extern "C" void kernel_launch(void* const* d_in, const int* in_sizes, int n_in,
                              void* d_out, int out_size, void* d_ws, size_t ws_size,
                              hipStream_t stream)
{
    const float* x   = (const float*)d_in[0];
    const float* Whx = (const float*)d_in[1];
    const float* Whh = (const float*)d_in[2];
    const float* bh  = (const float*)d_in[3];
    const float* Why = (const float*)d_in[4];
    const float* bo  = (const float*)d_in[5];
    float* out = (float*)d_out;
    __bf16* ws = (__bf16*)d_ws;

    // Zero H double-buffer (h0 = 0 reproduces the t==0 branch) + barrier counters.
    const size_t zero_bytes = (size_t)2*BATCH*HID*sizeof(__bf16) + (size_t)NROWG*64*sizeof(int);
    hipMemsetAsync(d_ws, 0, zero_bytes, stream);

    void* args[] = { &x, &Whx, &Whh, &bh, &Why, &bo, &out, &ws };
    hipLaunchCooperativeKernel((const void*)rnn_persistent,
                               dim3(NROWG*NCOLG), dim3(256), args, 0, stream);
}

// Round 2
// 1706.427 us; speedup vs baseline: 1.8212x; 1.8212x over previous
//
#include <hip/hip_runtime.h>
#include <hip/hip_bf16.h>

#define BATCH 256
#define SEQ   256
#define IND   128
#define HID   1024
#define OUTD  10

#define NCOLG 32           // 32 column groups of 32 cols
#define NROWG 8            // 8 row groups of 32 rows
#define CTR_OFF (2*BATCH*HID)   // counters after Hbuf, in bf16 elements

typedef __bf16 bf16x8 __attribute__((ext_vector_type(8)));
typedef float  f32x16 __attribute__((ext_vector_type(16)));
typedef unsigned long long u64;

union Pack4 { u64 q; __bf16 h[4]; };
union Pack8 { u64 q[2]; bf16x8 v; };

__device__ __forceinline__ float fast_tanh(float z) {
    float e = __expf(-2.0f * fabsf(z));
    float t = (1.0f - e) / (1.0f + e);
    return copysignf(t, z);
}

__global__ __launch_bounds__(256, 1)
void rnn_persistent(const float* __restrict__ x,
                    const float* __restrict__ Whx,
                    const float* __restrict__ Whh,
                    const float* __restrict__ bh,
                    const float* __restrict__ Why,
                    const float* __restrict__ bo,
                    float* __restrict__ out,
                    __bf16* __restrict__ ws)
{
    const int tid  = threadIdx.x;
    const int lane = tid & 63;
    const int wave = tid >> 6;
    const int bx   = blockIdx.x;
    const int colg = bx & (NCOLG-1);
    const int rowg = bx >> 5;
    const int c0 = colg * 32;
    const int r0 = rowg * 32;
    const int ln31  = lane & 31;
    const int lhalf = lane >> 5;

    __bf16* hb = ws;
    int* ctr = (int*)(ws + CTR_OFF) + rowg * 64;  // 256B-padded per group

    __shared__ float red[4][32][32];   // 16 KB: cross-wave K-reduction

    // ---- one-time: register-resident B fragments, hi/lo split ----
    // B-frag layout (32x32x16): n = lane&31, k = (lane>>5)*8 + j
    bf16x8 whh_hi[16], whh_lo[16];
    {
        const int nn = c0 + ln31;
        #pragma unroll
        for (int kk = 0; kk < 16; ++kk) {
            const int kb = wave*256 + kk*16 + lhalf*8;
            #pragma unroll
            for (int j = 0; j < 8; ++j) {
                float v = Whh[(size_t)(kb + j)*HID + nn];
                __bf16 h = (__bf16)v;
                whh_hi[kk][j] = h;
                whh_lo[kk][j] = (__bf16)(v - (float)h);
            }
        }
    }
    bf16x8 whx_hi[2], whx_lo[2];
    {
        const int nn = c0 + ln31;
        #pragma unroll
        for (int kk = 0; kk < 2; ++kk) {
            const int kb = wave*32 + kk*16 + lhalf*8;
            #pragma unroll
            for (int j = 0; j < 8; ++j) {
                float v = Whx[(size_t)(kb + j)*HID + nn];
                __bf16 h = (__bf16)v;
                whx_hi[kk][j] = h;
                whx_lo[kk][j] = (__bf16)(v - (float)h);
            }
        }
    }
    // Store/epilogue assignment: thread -> (row = tid>>3, cols cq..cq+3)
    const int srow = tid >> 3;
    const int scq  = (tid & 7) * 4;
    const float4 bh4 = *(const float4*)(bh + c0 + scq);
    const size_t xrow_base = (size_t)(r0 + ln31) * (SEQ*IND) + wave*32 + lhalf*8;

    for (int t = 0; t < SEQ; ++t) {
        const int cur = t & 1;
        const int nxt = cur ^ 1;
        f32x16 acc0{}, acc1{};

        // ---- x(t) contribution: independent of h(t), done BEFORE barrier wait.
        // 3-pass hi/lo split: AhiBhi + AhiBlo + AloBhi
        {
            const float* xp = x + xrow_base + (size_t)t*IND;
            #pragma unroll
            for (int kk = 0; kk < 2; ++kk) {
                const float4* p = (const float4*)(xp + kk*16);
                float4 v0 = p[0], v1 = p[1];
                float vv[8] = {v0.x,v0.y,v0.z,v0.w,v1.x,v1.y,v1.z,v1.w};
                bf16x8 ahi, alo;
                #pragma unroll
                for (int j = 0; j < 8; ++j) {
                    __bf16 h = (__bf16)vv[j];
                    ahi[j] = h;
                    alo[j] = (__bf16)(vv[j] - (float)h);
                }
                acc0 = __builtin_amdgcn_mfma_f32_32x32x16_bf16(ahi, whx_hi[kk], acc0, 0,0,0);
                acc1 = __builtin_amdgcn_mfma_f32_32x32x16_bf16(ahi, whx_lo[kk], acc1, 0,0,0);
                acc0 = __builtin_amdgcn_mfma_f32_32x32x16_bf16(alo, whx_hi[kk], acc0, 0,0,0);
            }
        }

        // ---- wait for h(t), then h(t) @ Whh. t==0: h0 == 0, skip entirely.
        if (t > 0) {
            if (tid == 0) {
                const int target = 32*t;
                // Relaxed agent load = global_load sc0 sc1: polls the coherence
                // point (LLC) directly; no cache-maintenance fence needed.
                while (__hip_atomic_load(ctr, __ATOMIC_RELAXED, __HIP_MEMORY_SCOPE_AGENT) < target) { }
            }
            __syncthreads();   // orders spin result before h loads for all waves

            // A-frag = 8 consecutive bf16 of row (r0+ln31), via two 8B
            // agent-scope loads (bypass L1/L2, read LLC where writers put h).
            const u64* ap = (const u64*)(hb + (size_t)cur*BATCH*HID
                                 + (size_t)(r0+ln31)*HID + wave*256 + lhalf*8);
            #pragma unroll
            for (int kk = 0; kk < 16; ++kk) {
                Pack8 p;
                p.q[0] = __hip_atomic_load(ap + kk*4,     __ATOMIC_RELAXED, __HIP_MEMORY_SCOPE_AGENT);
                p.q[1] = __hip_atomic_load(ap + kk*4 + 1, __ATOMIC_RELAXED, __HIP_MEMORY_SCOPE_AGENT);
                acc0 = __builtin_amdgcn_mfma_f32_32x32x16_bf16(p.v, whh_hi[kk], acc0, 0,0,0);
                acc1 = __builtin_amdgcn_mfma_f32_32x32x16_bf16(p.v, whh_lo[kk], acc1, 0,0,0);
            }
        }

        // ---- cross-wave K reduction through LDS
        // C/D layout (32x32): col=lane&31, row=(reg&3)+8*(reg>>2)+4*(lane>>5)
        #pragma unroll
        for (int r = 0; r < 16; ++r) {
            const int row = (r & 3) + 8*(r >> 2) + 4*lhalf;
            red[wave][row][ln31] = acc0[r] + acc1[r];
        }
        __syncthreads();
        {
            // thread -> (srow, cols scq..scq+3): float4 LDS reads, one 8B
            // write-through (sc0 sc1) store of 4 bf16 to the next h buffer.
            const float4 s0 = *(const float4*)&red[0][srow][scq];
            const float4 s1 = *(const float4*)&red[1][srow][scq];
            const float4 s2 = *(const float4*)&red[2][srow][scq];
            const float4 s3 = *(const float4*)&red[3][srow][scq];
            float z0 = s0.x + s1.x + s2.x + s3.x + bh4.x;
            float z1 = s0.y + s1.y + s2.y + s3.y + bh4.y;
            float z2 = s0.z + s1.z + s2.z + s3.z + bh4.z;
            float z3 = s0.w + s1.w + s2.w + s3.w + bh4.w;
            Pack4 pk;
            pk.h[0] = (__bf16)fast_tanh(z0);
            pk.h[1] = (__bf16)fast_tanh(z1);
            pk.h[2] = (__bf16)fast_tanh(z2);
            pk.h[3] = (__bf16)fast_tanh(z3);
            u64* hq = (u64*)(hb + (size_t)nxt*BATCH*HID + (size_t)(r0+srow)*HID + c0 + scq);
            __hip_atomic_store(hq, pk.q, __ATOMIC_RELAXED, __HIP_MEMORY_SCOPE_AGENT);
        }
        // Drains vmcnt(0) per wave before s_barrier => every wave's sc1 store
        // has reached the coherence point before tid0 publishes the arrival.
        __syncthreads();
        if (tid == 0) {
            __hip_atomic_fetch_add(ctr, 1, __ATOMIC_RELAXED, __HIP_MEMORY_SCOPE_AGENT);
        }
    }

    // ---- epilogue: colg==0 WG of each row-group computes o + softmax
    if (colg == 0) {
        if (tid == 0) {
            while (__hip_atomic_load(ctr, __ATOMIC_RELAXED, __HIP_MEMORY_SCOPE_AGENT) < 32*SEQ) { }
        }
        __syncthreads();
        // after t=255, final h is in buffer 0 (written with sc1 stores -> read agent-scope)
        float* obuf = &red[0][0][0];    // reuse LDS, 320 floats
        for (int idx = tid; idx < 32*OUTD; idx += 256) {
            const int row = idx / OUTD;
            const int c   = idx - row*OUTD;
            const u64* hq = (const u64*)(hb + (size_t)(r0+row)*HID);
            float s = bo[c];
            #pragma unroll 8
            for (int k4 = 0; k4 < HID/4; ++k4) {
                Pack4 p;
                p.q = __hip_atomic_load(hq + k4, __ATOMIC_RELAXED, __HIP_MEMORY_SCOPE_AGENT);
                const float* wr = Why + (size_t)k4*4*OUTD + c;
                s += (float)p.h[0]*wr[0] + (float)p.h[1]*wr[OUTD]
                   + (float)p.h[2]*wr[2*OUTD] + (float)p.h[3]*wr[3*OUTD];
            }
            obuf[idx] = s;
        }
        __syncthreads();
        if (tid < 32) {
            float m = -1e30f;
            #pragma unroll
            for (int c = 0; c < OUTD; ++c) m = fmaxf(m, obuf[tid*OUTD+c]);
            float e[OUTD]; float ssum = 0.f;
            #pragma unroll
            for (int c = 0; c < OUTD; ++c) { e[c] = __expf(obuf[tid*OUTD+c] - m); ssum += e[c]; }
            const float inv = 1.0f / ssum;
            #pragma unroll
            for (int c = 0; c < OUTD; ++c) out[(size_t)(r0+tid)*OUTD + c] = e[c]*inv;
        }
    }
}

extern "C" void kernel_launch(void* const* d_in, const int* in_sizes, int n_in,
                              void* d_out, int out_size, void* d_ws, size_t ws_size,
                              hipStream_t stream)
{
    const float* x   = (const float*)d_in[0];
    const float* Whx = (const float*)d_in[1];
    const float* Whh = (const float*)d_in[2];
    const float* bh  = (const float*)d_in[3];
    const float* Why = (const float*)d_in[4];
    const float* bo  = (const float*)d_in[5];
    float* out = (float*)d_out;
    __bf16* ws = (__bf16*)d_ws;

    // Only the barrier counters need zeroing (t==0 skips reading h: h0 == 0).
    hipMemsetAsync((char*)d_ws + (size_t)CTR_OFF*sizeof(__bf16), 0,
                   (size_t)NROWG*64*sizeof(int), stream);

    void* args[] = { &x, &Whx, &Whh, &bh, &Why, &bo, &out, &ws };
    hipLaunchCooperativeKernel((const void*)rnn_persistent,
                               dim3(NROWG*NCOLG), dim3(256), args, 0, stream);
}

// Round 4
// 1666.189 us; speedup vs baseline: 1.8652x; 1.0241x over previous
//
#include <hip/hip_runtime.h>
#include <hip/hip_bf16.h>

#define BATCH 256
#define SEQ   256
#define IND   128
#define HID   1024
#define OUTD  10

#define NCOLG 32           // 32 column groups of 32 cols
#define NROWG 8            // 8 row groups of 32 rows
#define CTR_OFF (2*BATCH*HID)   // flags after Hbuf, in bf16 elements
                                // flags region: NROWG*32 ints = 1 KB (< R2's proven 2 KB)

typedef __bf16 bf16x8 __attribute__((ext_vector_type(8)));
typedef float  f32x16 __attribute__((ext_vector_type(16)));
typedef unsigned long long u64;

union Pack4 { u64 q; __bf16 h[4]; };
union Pack8 { u64 q[2]; bf16x8 v; };

__device__ __forceinline__ float fast_tanh(float z) {
    float e = __expf(-2.0f * fabsf(z));
    float t = (1.0f - e) / (1.0f + e);
    return copysignf(t, z);
}

__global__ __launch_bounds__(256, 1)
void rnn_persistent(const float* __restrict__ x,
                    const float* __restrict__ Whx,
                    const float* __restrict__ Whh,
                    const float* __restrict__ bh,
                    const float* __restrict__ Why,
                    const float* __restrict__ bo,
                    float* __restrict__ out,
                    __bf16* __restrict__ ws)
{
    const int tid  = threadIdx.x;
    const int lane = tid & 63;
    const int wave = tid >> 6;
    const int bx   = blockIdx.x;
    const int colg = bx & (NCOLG-1);
    const int rowg = bx >> 5;
    const int c0 = colg * 32;
    const int r0 = rowg * 32;
    const int ln31  = lane & 31;
    const int lhalf = lane >> 5;

    __bf16* hb = ws;
    // Per-WG flags: 32 ints (one 128-B line) per row-group. Monotone t+1.
    // Producers write distinct ints (no RMW); consumers read the whole line
    // with one 64-lane vector load (lanes 32-63 replicate lanes 0-31).
    int* flags  = (int*)(ws + CTR_OFF);
    int* myflag = flags + rowg*32 + colg;
    int* pollp  = flags + rowg*32 + ln31;

    __shared__ float red[4][32][32];   // 16 KB: cross-wave K-reduction

    // ---- one-time: register-resident B fragments, hi/lo split ----
    // B-frag layout (32x32x16): n = lane&31, k = (lane>>5)*8 + j
    bf16x8 whh_hi[16], whh_lo[16];
    {
        const int nn = c0 + ln31;
        #pragma unroll
        for (int kk = 0; kk < 16; ++kk) {
            const int kb = wave*256 + kk*16 + lhalf*8;
            #pragma unroll
            for (int j = 0; j < 8; ++j) {
                float v = Whh[(size_t)(kb + j)*HID + nn];
                __bf16 h = (__bf16)v;
                whh_hi[kk][j] = h;
                whh_lo[kk][j] = (__bf16)(v - (float)h);
            }
        }
    }
    bf16x8 whx_hi[2], whx_lo[2];
    {
        const int nn = c0 + ln31;
        #pragma unroll
        for (int kk = 0; kk < 2; ++kk) {
            const int kb = wave*32 + kk*16 + lhalf*8;
            #pragma unroll
            for (int j = 0; j < 8; ++j) {
                float v = Whx[(size_t)(kb + j)*HID + nn];
                __bf16 h = (__bf16)v;
                whx_hi[kk][j] = h;
                whx_lo[kk][j] = (__bf16)(v - (float)h);
            }
        }
    }
    // Store/epilogue assignment: thread -> (row = tid>>3, cols cq..cq+3)
    const int srow = tid >> 3;
    const int scq  = (tid & 7) * 4;
    const float4 bh4 = *(const float4*)(bh + c0 + scq);
    const size_t xrow_base = (size_t)(r0 + ln31) * (SEQ*IND) + wave*32 + lhalf*8;

    for (int t = 0; t < SEQ; ++t) {
        const int cur = t & 1;
        const int nxt = cur ^ 1;
        f32x16 acc0{}, acc1{};

        // ---- x(t) contribution: independent of h(t), done BEFORE the flag
        // poll (overlaps flag/store propagation from the previous step).
        // 3-pass hi/lo split: AhiBhi + AhiBlo + AloBhi
        {
            const float* xp = x + xrow_base + (size_t)t*IND;
            #pragma unroll
            for (int kk = 0; kk < 2; ++kk) {
                const float4* p = (const float4*)(xp + kk*16);
                float4 v0 = p[0], v1 = p[1];
                float vv[8] = {v0.x,v0.y,v0.z,v0.w,v1.x,v1.y,v1.z,v1.w};
                bf16x8 ahi, alo;
                #pragma unroll
                for (int j = 0; j < 8; ++j) {
                    __bf16 h = (__bf16)vv[j];
                    ahi[j] = h;
                    alo[j] = (__bf16)(vv[j] - (float)h);
                }
                acc0 = __builtin_amdgcn_mfma_f32_32x32x16_bf16(ahi, whx_hi[kk], acc0, 0,0,0);
                acc1 = __builtin_amdgcn_mfma_f32_32x32x16_bf16(ahi, whx_lo[kk], acc1, 0,0,0);
                acc0 = __builtin_amdgcn_mfma_f32_32x32x16_bf16(alo, whx_hi[kk], acc0, 0,0,0);
            }
        }

        // ---- wait for h(t), then h(t) @ Whh. t==0: h0 == 0, skip entirely.
        if (t > 0) {
            // All 4 waves poll the 32 flags of this row-group (one vector
            // load of a 128-B line at the coherence point per iteration).
            for (;;) {
                int v = __hip_atomic_load(pollp, __ATOMIC_RELAXED, __HIP_MEMORY_SCOPE_AGENT);
                if (__all(v >= t)) break;
            }
            __syncthreads();   // orders poll result before h loads (HW + compiler)

            // A-frag = 8 consecutive bf16 of row (r0+ln31), via two 8B
            // agent-scope loads (bypass L1/L2, read LLC where writers put h).
            const u64* ap = (const u64*)(hb + (size_t)cur*BATCH*HID
                                 + (size_t)(r0+ln31)*HID + wave*256 + lhalf*8);
            #pragma unroll
            for (int kk = 0; kk < 16; ++kk) {
                Pack8 p;
                p.q[0] = __hip_atomic_load(ap + kk*4,     __ATOMIC_RELAXED, __HIP_MEMORY_SCOPE_AGENT);
                p.q[1] = __hip_atomic_load(ap + kk*4 + 1, __ATOMIC_RELAXED, __HIP_MEMORY_SCOPE_AGENT);
                acc0 = __builtin_amdgcn_mfma_f32_32x32x16_bf16(p.v, whh_hi[kk], acc0, 0,0,0);
                acc1 = __builtin_amdgcn_mfma_f32_32x32x16_bf16(p.v, whh_lo[kk], acc1, 0,0,0);
            }
        }

        // ---- cross-wave K reduction through LDS
        // C/D layout (32x32): col=lane&31, row=(reg&3)+8*(reg>>2)+4*(lane>>5)
        #pragma unroll
        for (int r = 0; r < 16; ++r) {
            const int row = (r & 3) + 8*(r >> 2) + 4*lhalf;
            red[wave][row][ln31] = acc0[r] + acc1[r];
        }
        __syncthreads();
        {
            // thread -> (srow, cols scq..scq+3): float4 LDS reads, one 8B
            // write-through (sc0 sc1) store of 4 bf16 to the next h buffer.
            const float4 s0 = *(const float4*)&red[0][srow][scq];
            const float4 s1 = *(const float4*)&red[1][srow][scq];
            const float4 s2 = *(const float4*)&red[2][srow][scq];
            const float4 s3 = *(const float4*)&red[3][srow][scq];
            float z0 = s0.x + s1.x + s2.x + s3.x + bh4.x;
            float z1 = s0.y + s1.y + s2.y + s3.y + bh4.y;
            float z2 = s0.z + s1.z + s2.z + s3.z + bh4.z;
            float z3 = s0.w + s1.w + s2.w + s3.w + bh4.w;
            Pack4 pk;
            pk.h[0] = (__bf16)fast_tanh(z0);
            pk.h[1] = (__bf16)fast_tanh(z1);
            pk.h[2] = (__bf16)fast_tanh(z2);
            pk.h[3] = (__bf16)fast_tanh(z3);
            u64* hq = (u64*)(hb + (size_t)nxt*BATCH*HID + (size_t)(r0+srow)*HID + c0 + scq);
            __hip_atomic_store(hq, pk.q, __ATOMIC_RELAXED, __HIP_MEMORY_SCOPE_AGENT);
        }
        // Drains vmcnt(0) per wave before s_barrier => every wave's sc1 store
        // has reached the coherence point before tid0 publishes the arrival.
        __syncthreads();
        if (tid == 0) {
            __hip_atomic_store(myflag, t + 1, __ATOMIC_RELAXED, __HIP_MEMORY_SCOPE_AGENT);
        }
    }

    // ---- epilogue: colg==0 WG of each row-group computes o + softmax
    if (colg == 0) {
        for (;;) {
            int v = __hip_atomic_load(pollp, __ATOMIC_RELAXED, __HIP_MEMORY_SCOPE_AGENT);
            if (__all(v >= SEQ)) break;
        }
        __syncthreads();
        // after t=255, final h is in buffer 0 (written with sc1 stores -> read agent-scope)
        float* obuf = &red[0][0][0];    // reuse LDS, 320 floats
        for (int idx = tid; idx < 32*OUTD; idx += 256) {
            const int row = idx / OUTD;
            const int c   = idx - row*OUTD;
            const u64* hq = (const u64*)(hb + (size_t)(r0+row)*HID);
            float s = bo[c];
            #pragma unroll 8
            for (int k4 = 0; k4 < HID/4; ++k4) {
                Pack4 p;
                p.q = __hip_atomic_load(hq + k4, __ATOMIC_RELAXED, __HIP_MEMORY_SCOPE_AGENT);
                const float* wr = Why + (size_t)k4*4*OUTD + c;
                s += (float)p.h[0]*wr[0] + (float)p.h[1]*wr[OUTD]
                   + (float)p.h[2]*wr[2*OUTD] + (float)p.h[3]*wr[3*OUTD];
            }
            obuf[idx] = s;
        }
        __syncthreads();
        if (tid < 32) {
            float m = -1e30f;
            #pragma unroll
            for (int c = 0; c < OUTD; ++c) m = fmaxf(m, obuf[tid*OUTD+c]);
            float e[OUTD]; float ssum = 0.f;
            #pragma unroll
            for (int c = 0; c < OUTD; ++c) { e[c] = __expf(obuf[tid*OUTD+c] - m); ssum += e[c]; }
            const float inv = 1.0f / ssum;
            #pragma unroll
            for (int c = 0; c < OUTD; ++c) out[(size_t)(r0+tid)*OUTD + c] = e[c]*inv;
        }
    }
}

extern "C" void kernel_launch(void* const* d_in, const int* in_sizes, int n_in,
                              void* d_out, int out_size, void* d_ws, size_t ws_size,
                              hipStream_t stream)
{
    const float* x   = (const float*)d_in[0];
    const float* Whx = (const float*)d_in[1];
    const float* Whh = (const float*)d_in[2];
    const float* bh  = (const float*)d_in[3];
    const float* Why = (const float*)d_in[4];
    const float* bo  = (const float*)d_in[5];
    float* out = (float*)d_out;
    __bf16* ws = (__bf16*)d_ws;

    // Zero the flag region. Same offset and same 2 KB extent as the passing
    // R2 kernel (flags only occupy the first 1 KB of it).
    hipMemsetAsync((char*)d_ws + (size_t)CTR_OFF*sizeof(__bf16), 0,
                   (size_t)NROWG*64*sizeof(int), stream);

    void* args[] = { &x, &Whx, &Whh, &bh, &Why, &bo, &out, &ws };
    hipLaunchCooperativeKernel((const void*)rnn_persistent,
                               dim3(NROWG*NCOLG), dim3(256), args, 0, stream);
}

// Round 6
// 1288.600 us; speedup vs baseline: 2.4117x; 1.2930x over previous
//
#include <hip/hip_runtime.h>
#include <hip/hip_bf16.h>

#define BATCH 256
#define SEQ   256
#define IND   128
#define HID   1024
#define OUTD  10

#define NCOLG 32           // 32 column groups of 32 cols (R4-proven topology)
#define NROWG 8            // 8 row groups of 32 rows
#define ROWG_ELEMS (HID*32)     // one rowg h-tile: 32768 bf16 = 64 KB
#define CTR_OFF (2*BATCH*HID)   // flags after the two H buffers (same as R2/R4)

typedef __bf16 bf16x8 __attribute__((ext_vector_type(8)));
typedef float  f32x16 __attribute__((ext_vector_type(16)));
typedef unsigned long long u64;

union Pack4 { u64 q; __bf16 h[4]; };
union Pack8 { u64 q[2]; bf16x8 v; };

__device__ __forceinline__ float fast_tanh(float z) {
    float e = __expf(-2.0f * fabsf(z));
    float t = (1.0f - e) / (1.0f + e);
    return copysignf(t, z);
}

__global__ __launch_bounds__(256, 1)
void rnn_persistent(const float* __restrict__ x,
                    const float* __restrict__ Whx,
                    const float* __restrict__ Whh,
                    const float* __restrict__ bh,
                    const float* __restrict__ Why,
                    const float* __restrict__ bo,
                    float* __restrict__ out,
                    __bf16* __restrict__ ws)
{
    const int tid  = threadIdx.x;
    const int lane = tid & 63;
    const int wave = tid >> 6;
    const int bx   = blockIdx.x;
    const int colg = bx & (NCOLG-1);
    const int rowg = bx >> 5;
    const int c0 = colg * 32;
    const int r0 = rowg * 32;
    const int ln31  = lane & 31;
    const int lhalf = lane >> 5;

    __bf16* hb = ws;
    // Per-WG flags: BIT-IDENTICAL to passing R4.
    int* flags  = (int*)(ws + CTR_OFF);
    int* myflag = flags + rowg*32 + colg;
    int* pollp  = flags + rowg*32 + ln31;

    __shared__ float red[4][32][32];   // 16 KB: cross-wave K-reduction

    // ---- one-time: register-resident B fragments, hi/lo split (as R4) ----
    // B-frag layout (32x32x16): n = lane&31, k = (lane>>5)*8 + j
    bf16x8 whh_hi[16], whh_lo[16];
    {
        const int nn = c0 + ln31;
        #pragma unroll
        for (int kk = 0; kk < 16; ++kk) {
            const int kb = wave*256 + kk*16 + lhalf*8;
            #pragma unroll
            for (int j = 0; j < 8; ++j) {
                float v = Whh[(size_t)(kb + j)*HID + nn];
                __bf16 h = (__bf16)v;
                whh_hi[kk][j] = h;
                whh_lo[kk][j] = (__bf16)(v - (float)h);
            }
        }
    }
    bf16x8 whx_hi[2], whx_lo[2];
    {
        const int nn = c0 + ln31;
        #pragma unroll
        for (int kk = 0; kk < 2; ++kk) {
            const int kb = wave*32 + kk*16 + lhalf*8;
            #pragma unroll
            for (int j = 0; j < 8; ++j) {
                float v = Whx[(size_t)(kb + j)*HID + nn];
                __bf16 h = (__bf16)v;
                whx_hi[kk][j] = h;
                whx_lo[kk][j] = (__bf16)(v - (float)h);
            }
        }
    }
    // Store/epilogue assignment: thread -> (row = tid>>3, cols scq..scq+3)
    const int srow = tid >> 3;
    const int scq  = (tid & 7) * 4;
    const float4 bh4 = *(const float4*)(bh + c0 + scq);
    const size_t xrow_base = (size_t)(r0 + ln31) * (SEQ*IND) + wave*32 + lhalf*8;
    // K-blocked lane-contiguous h layout, per (buf, rowg) region of 8192 u64:
    //   u64 index = kb*128 + ((k16>>3)*32 + m)*2 + ((k16>>2)&1)
    // where kb = k/16, k16 = k%16, m = row - r0. A-frag reader: lane reads
    // u64s kb*128 + lane*2 + {0,1}  (dense 1 KB per wave per kb).
    const int sc  = c0 + scq;                 // first of this thread's 4 cols
    const int soffq = (sc >> 4)*128 + (((sc >> 3) & 1)*32 + srow)*2 + ((sc >> 2) & 1);

    for (int t = 0; t < SEQ; ++t) {
        const int cur = t & 1;
        const int nxt = cur ^ 1;
        f32x16 acc0{}, acc1{};

        // ---- x(t) contribution: h-independent, overlaps flag/store latency.
        // 3-pass hi/lo split: AhiBhi + AhiBlo + AloBhi  (bit-identical to R4)
        {
            const float* xp = x + xrow_base + (size_t)t*IND;
            #pragma unroll
            for (int kk = 0; kk < 2; ++kk) {
                const float4* p = (const float4*)(xp + kk*16);
                float4 v0 = p[0], v1 = p[1];
                float vv[8] = {v0.x,v0.y,v0.z,v0.w,v1.x,v1.y,v1.z,v1.w};
                bf16x8 ahi, alo;
                #pragma unroll
                for (int j = 0; j < 8; ++j) {
                    __bf16 h = (__bf16)vv[j];
                    ahi[j] = h;
                    alo[j] = (__bf16)(vv[j] - (float)h);
                }
                acc0 = __builtin_amdgcn_mfma_f32_32x32x16_bf16(ahi, whx_hi[kk], acc0, 0,0,0);
                acc1 = __builtin_amdgcn_mfma_f32_32x32x16_bf16(ahi, whx_lo[kk], acc1, 0,0,0);
                acc0 = __builtin_amdgcn_mfma_f32_32x32x16_bf16(alo, whx_hi[kk], acc0, 0,0,0);
            }
        }

        // ---- wait for h(t), then h(t) @ Whh. t==0: h0 == 0, skip entirely.
        if (t > 0) {
            for (;;) {
                int v = __hip_atomic_load(pollp, __ATOMIC_RELAXED, __HIP_MEMORY_SCOPE_AGENT);
                if (__all(v >= t)) break;
            }
            __syncthreads();   // orders poll result before h loads (HW + compiler)

            // A-frag from K-blocked lane-contiguous buffer: two 8B loads/lane
            // over a dense 1 KB span per kb (vs 32-line scatter in R4).
            const u64* hq = (const u64*)(hb + (size_t)(cur*NROWG + rowg)*ROWG_ELEMS);
            #pragma unroll
            for (int kk = 0; kk < 16; ++kk) {
                const int idx = (wave*16 + kk)*128 + lane*2;
                Pack8 p;
                p.q[0] = __hip_atomic_load(hq + idx,     __ATOMIC_RELAXED, __HIP_MEMORY_SCOPE_AGENT);
                p.q[1] = __hip_atomic_load(hq + idx + 1, __ATOMIC_RELAXED, __HIP_MEMORY_SCOPE_AGENT);
                acc0 = __builtin_amdgcn_mfma_f32_32x32x16_bf16(p.v, whh_hi[kk], acc0, 0,0,0);
                acc1 = __builtin_amdgcn_mfma_f32_32x32x16_bf16(p.v, whh_lo[kk], acc1, 0,0,0);
            }
        }

        // ---- cross-wave K reduction through LDS
        // C/D layout (32x32): col=lane&31, row=(reg&3)+8*(reg>>2)+4*(lane>>5)
        #pragma unroll
        for (int r = 0; r < 16; ++r) {
            const int row = (r & 3) + 8*(r >> 2) + 4*lhalf;
            red[wave][row][ln31] = acc0[r] + acc1[r];
        }
        __syncthreads();
        {
            // thread -> (srow, cols scq..scq+3): float4 LDS reads, one 8B
            // write-through store into the K-blocked buffer.
            const float4 s0 = *(const float4*)&red[0][srow][scq];
            const float4 s1 = *(const float4*)&red[1][srow][scq];
            const float4 s2 = *(const float4*)&red[2][srow][scq];
            const float4 s3 = *(const float4*)&red[3][srow][scq];
            float z0 = s0.x + s1.x + s2.x + s3.x + bh4.x;
            float z1 = s0.y + s1.y + s2.y + s3.y + bh4.y;
            float z2 = s0.z + s1.z + s2.z + s3.z + bh4.z;
            float z3 = s0.w + s1.w + s2.w + s3.w + bh4.w;
            Pack4 pk;
            pk.h[0] = (__bf16)fast_tanh(z0);
            pk.h[1] = (__bf16)fast_tanh(z1);
            pk.h[2] = (__bf16)fast_tanh(z2);
            pk.h[3] = (__bf16)fast_tanh(z3);
            u64* hnq = (u64*)(hb + (size_t)(nxt*NROWG + rowg)*ROWG_ELEMS) + soffq;
            __hip_atomic_store(hnq, pk.q, __ATOMIC_RELAXED, __HIP_MEMORY_SCOPE_AGENT);
        }
        // __syncthreads drains vmcnt(0) per wave => every wave's sc1 store
        // reached the coherence point before tid0 publishes the arrival.
        __syncthreads();
        if (tid == 0) {
            __hip_atomic_store(myflag, t + 1, __ATOMIC_RELAXED, __HIP_MEMORY_SCOPE_AGENT);
        }
    }

    // ---- epilogue: colg==0 WG of each row-group computes o + softmax
    if (colg == 0) {
        for (;;) {
            int v = __hip_atomic_load(pollp, __ATOMIC_RELAXED, __HIP_MEMORY_SCOPE_AGENT);
            if (__all(v >= SEQ)) break;
        }
        __syncthreads();
        // after t=255, final h is in buffer 0 (K-blocked lane-contiguous layout)
        const u64* hq0 = (const u64*)(hb + (size_t)(0*NROWG + rowg)*ROWG_ELEMS);
        float* obuf = &red[0][0][0];    // reuse LDS, 320 floats
        for (int idx = tid; idx < 32*OUTD; idx += 256) {
            const int row = idx / OUTD;      // m within rowg
            const int c   = idx - row*OUTD;
            float s = bo[c];
            #pragma unroll 8
            for (int k4 = 0; k4 < HID/4; ++k4) {
                const int k = k4*4;
                Pack4 p;
                p.q = __hip_atomic_load(hq0 + (k>>4)*128 + (((k>>3)&1)*32 + row)*2 + ((k>>2)&1),
                                        __ATOMIC_RELAXED, __HIP_MEMORY_SCOPE_AGENT);
                const float* wr = Why + (size_t)k*OUTD + c;
                s += (float)p.h[0]*wr[0] + (float)p.h[1]*wr[OUTD]
                   + (float)p.h[2]*wr[2*OUTD] + (float)p.h[3]*wr[3*OUTD];
            }
            obuf[idx] = s;
        }
        __syncthreads();
        if (tid < 32) {
            float m = -1e30f;
            #pragma unroll
            for (int c = 0; c < OUTD; ++c) m = fmaxf(m, obuf[tid*OUTD+c]);
            float e[OUTD]; float ssum = 0.f;
            #pragma unroll
            for (int c = 0; c < OUTD; ++c) { e[c] = __expf(obuf[tid*OUTD+c] - m); ssum += e[c]; }
            const float inv = 1.0f / ssum;
            #pragma unroll
            for (int c = 0; c < OUTD; ++c) out[(size_t)(r0+tid)*OUTD + c] = e[c]*inv;
        }
    }
}

extern "C" void kernel_launch(void* const* d_in, const int* in_sizes, int n_in,
                              void* d_out, int out_size, void* d_ws, size_t ws_size,
                              hipStream_t stream)
{
    const float* x   = (const float*)d_in[0];
    const float* Whx = (const float*)d_in[1];
    const float* Whh = (const float*)d_in[2];
    const float* bh  = (const float*)d_in[3];
    const float* Why = (const float*)d_in[4];
    const float* bo  = (const float*)d_in[5];
    float* out = (float*)d_out;
    __bf16* ws = (__bf16*)d_ws;

    // Zero the flag region: SAME offset and SAME 2 KB extent as passing R4.
    hipMemsetAsync((char*)d_ws + (size_t)CTR_OFF*sizeof(__bf16), 0,
                   (size_t)NROWG*64*sizeof(int), stream);

    void* args[] = { &x, &Whx, &Whh, &bh, &Why, &bo, &out, &ws };
    hipLaunchCooperativeKernel((const void*)rnn_persistent,
                               dim3(NROWG*NCOLG), dim3(256), args, 0, stream);
}